// Round 17
// baseline (161.743 us; speedup 1.0000x reference)
//
#include <hip/hip_runtime.h>
#include <hip/hip_bf16.h>

#define T_SEQ 2048
#define NB 4
#define NH 16
#define DK 64
#define DM 1024
#define QKS 3072  // row stride of fused [Q|K|V] buffer

typedef __attribute__((ext_vector_type(8))) __bf16 bf16x8;
typedef __attribute__((ext_vector_type(4))) __bf16 bf16x4;
typedef __attribute__((ext_vector_type(4))) float f32x4;
typedef __attribute__((ext_vector_type(2))) int i32x2;
typedef __attribute__((ext_vector_type(4))) int i32x4;

// async global->LDS, 16B per lane, wave-uniform LDS base + lane*16
__device__ __forceinline__ void gl_lds16(const __bf16* g, __bf16* l) {
  __builtin_amdgcn_global_load_lds(
      (const __attribute__((address_space(1))) void*)g,
      (__attribute__((address_space(3))) void*)l,
      16, 0, 0);
}

__device__ __forceinline__ unsigned cvt_pk_bf16(float lo, float hi) {
  unsigned r;
  asm("v_cvt_pk_bf16_f32 %0, %1, %2" : "=v"(r) : "v"(lo), "v"(hi));
  return r;
}

// ---------------- fused cast: X + all four weights, one dispatch ----------
__global__ __launch_bounds__(256) void cast_all(const float* __restrict__ X,
                                                const float* __restrict__ Wq,
                                                const float* __restrict__ Wk,
                                                const float* __restrict__ Wv,
                                                const float* __restrict__ Wo,
                                                __bf16* __restrict__ Xb,
                                                __bf16* __restrict__ Wqb,
                                                __bf16* __restrict__ Wkb,
                                                __bf16* __restrict__ Wvb,
                                                __bf16* __restrict__ Wob) {
  const int NX4 = NB * T_SEQ * DM / 4;  // 2,097,152
  const int NW4 = DM * DM / 4;          // 262,144 (= 1<<18)
  int i = blockIdx.x * 256 + threadIdx.x;
  const float* in;
  __bf16* out;
  int idx;
  if (i < NX4) {
    in = X; out = Xb; idx = i;
  } else {
    const int j = i - NX4;
    const int w = j >> 18;
    idx = j & (NW4 - 1);
    in = (w == 0) ? Wq : (w == 1) ? Wk : (w == 2) ? Wv : Wo;
    out = (w == 0) ? Wqb : (w == 1) ? Wkb : (w == 2) ? Wvb : Wob;
  }
  float4 v = reinterpret_cast<const float4*>(in)[idx];
  bf16x4 o;
  o[0] = (__bf16)v.x; o[1] = (__bf16)v.y; o[2] = (__bf16)v.z; o[3] = (__bf16)v.w;
  reinterpret_cast<bf16x4*>(out)[idx] = o;
}

// ---------------- 256x256 8-phase GEMM (T3+T4+T5): C = A * B^T ------------
template<int DO_QSCALE>
__global__ __launch_bounds__(512, 2) void gemm_nt_8p(const __bf16* __restrict__ A,
                                                     const __bf16* __restrict__ Bm,
                                                     __bf16* __restrict__ C,
                                                     int M, int N, int K) {
  __shared__ alignas(16) __bf16 As[2][256][64];
  __shared__ alignas(16) __bf16 Bs[2][256][64];
  const int tid = threadIdx.x;
  const int wid = tid >> 6, l = tid & 63, lg = l >> 4, lr = l & 15;
  const int wm = wid >> 2, wn = wid & 3;
  // bijective XCD swizzle (gridDim.x % 8 == 0)
  const int f = (int)blockIdx.x;
  const int cpx = (int)gridDim.x >> 3;
  const int swz = (f & 7) * cpx + (f >> 3);
  const int nbn = N >> 8;
  const int m0 = (swz / nbn) << 8, n0 = (swz % nbn) << 8;

  const int srow = l >> 3;
  const int schunk = (l & 7) ^ srow;  // inverse-swizzled source chunk
  const int rsw = lr & 7;
  const int strow = wid * 8 + srow;   // staging row within a 64-row group

  f32x4 acc[8][4] = {};
  bf16x8 aA[8], bB[8];

  auto SA = [&](int buf, int half, int t) {
    #pragma unroll
    for (int j = 0; j < 2; ++j)
      gl_lds16(A + (size_t)(m0 + half * 128 + j * 64 + strow) * K + t * 64 + schunk * 8,
               &As[buf][half * 128 + j * 64 + wid * 8][0]);
  };
  auto SB = [&](int buf, int half, int t) {
    #pragma unroll
    for (int j = 0; j < 2; ++j)
      gl_lds16(Bm + (size_t)(n0 + half * 128 + j * 64 + strow) * K + t * 64 + schunk * 8,
               &Bs[buf][half * 128 + j * 64 + wid * 8][0]);
  };
  auto LA = [&](int buf, int mh) {
    #pragma unroll
    for (int mt = 0; mt < 4; ++mt) {
      const char* p = (const char*)&As[buf][wm * 128 + mh * 64 + mt * 16 + lr][0];
      aA[mt * 2 + 0] = *reinterpret_cast<const bf16x8*>(p + ((lg ^ rsw) << 4));
      aA[mt * 2 + 1] = *reinterpret_cast<const bf16x8*>(p + (((4 + lg) ^ rsw) << 4));
    }
  };
  auto LBh = [&](int buf, int nh) {
    #pragma unroll
    for (int ntl = 0; ntl < 2; ++ntl) {
      const int nt = nh * 2 + ntl;
      const char* p = (const char*)&Bs[buf][wn * 64 + nt * 16 + lr][0];
      bB[nt * 2 + 0] = *reinterpret_cast<const bf16x8*>(p + ((lg ^ rsw) << 4));
      bB[nt * 2 + 1] = *reinterpret_cast<const bf16x8*>(p + (((4 + lg) ^ rsw) << 4));
    }
  };
  auto MQ = [&](int mh, int nh) {
    #pragma unroll
    for (int mt = 0; mt < 4; ++mt)
      #pragma unroll
      for (int ntl = 0; ntl < 2; ++ntl) {
        const int nt = nh * 2 + ntl;
        acc[mh * 4 + mt][nt] = __builtin_amdgcn_mfma_f32_16x16x32_bf16(
            aA[mt * 2 + 0], bB[nt * 2 + 0], acc[mh * 4 + mt][nt], 0, 0, 0);
        acc[mh * 4 + mt][nt] = __builtin_amdgcn_mfma_f32_16x16x32_bf16(
            aA[mt * 2 + 1], bB[nt * 2 + 1], acc[mh * 4 + mt][nt], 0, 0, 0);
      }
  };
  #define WAIT_LGKM() do { asm volatile("s_waitcnt lgkmcnt(0)" ::: "memory"); \
                           __builtin_amdgcn_sched_barrier(0); } while (0)

  // prologue: tile0 full (8) + tile1 {B0,B1,A0} (6) = 14 outstanding
  SB(0, 0, 0); SB(0, 1, 0); SA(0, 0, 0); SA(0, 1, 0);
  SB(1, 0, 1); SB(1, 1, 1); SA(1, 0, 1);
  asm volatile("s_waitcnt vmcnt(6)" ::: "memory");  // tile0 landed
  __builtin_amdgcn_s_barrier();

  const int NIT = K >> 7;
  for (int i = 0; i < NIT; ++i) {
    const bool lastit = (i == NIT - 1);
    const int t2 = 2 * i + 2, t3 = 2 * i + 3;
    // P1: reads A0h0+B-nh0 (12); stage tile(2i+1).Ah1
    LA(0, 0); LBh(0, 0);
    SA(1, 1, 2 * i + 1);
    __builtin_amdgcn_s_barrier();
    WAIT_LGKM();
    __builtin_amdgcn_s_setprio(1); MQ(0, 0); __builtin_amdgcn_s_setprio(0);
    __builtin_amdgcn_s_barrier();
    // P2: reads B-nh1 (4); no staging
    LBh(0, 1);
    WAIT_LGKM();
    __builtin_amdgcn_s_setprio(1); MQ(0, 1); __builtin_amdgcn_s_setprio(0);
    __builtin_amdgcn_s_barrier();
    // P3: reads A0h1 (8); stage t+2.B both halves
    LA(0, 1);
    if (!lastit) { SB(0, 0, t2); SB(0, 1, t2); }
    __builtin_amdgcn_s_barrier();
    WAIT_LGKM();
    __builtin_amdgcn_s_setprio(1); MQ(1, 1); __builtin_amdgcn_s_setprio(0);
    __builtin_amdgcn_s_barrier();
    // P4: stage t+2.Ah0; wait tile 2i+1 landed
    if (!lastit) SA(0, 0, t2);
    __builtin_amdgcn_s_setprio(1); MQ(1, 0); __builtin_amdgcn_s_setprio(0);
    if (lastit) asm volatile("s_waitcnt vmcnt(0)" ::: "memory");
    else        asm volatile("s_waitcnt vmcnt(6)" ::: "memory");
    __builtin_amdgcn_s_barrier();
    // P5: reads buf1 A0h0+B-nh0 (12); stage t+2.Ah1
    LA(1, 0); LBh(1, 0);
    if (!lastit) SA(0, 1, t2);
    __builtin_amdgcn_s_barrier();
    WAIT_LGKM();
    __builtin_amdgcn_s_setprio(1); MQ(0, 0); __builtin_amdgcn_s_setprio(0);
    __builtin_amdgcn_s_barrier();
    // P6: reads B-nh1 (4); no staging
    LBh(1, 1);
    WAIT_LGKM();
    __builtin_amdgcn_s_setprio(1); MQ(0, 1); __builtin_amdgcn_s_setprio(0);
    __builtin_amdgcn_s_barrier();
    // P7: reads A1h1 (8); stage t+3.B both halves
    LA(1, 1);
    if (!lastit) { SB(1, 0, t3); SB(1, 1, t3); }
    __builtin_amdgcn_s_barrier();
    WAIT_LGKM();
    __builtin_amdgcn_s_setprio(1); MQ(1, 1); __builtin_amdgcn_s_setprio(0);
    __builtin_amdgcn_s_barrier();
    // P8: stage t+3.Ah0; wait tile 2i+2 landed
    if (!lastit) SA(1, 0, t3);
    __builtin_amdgcn_s_setprio(1); MQ(1, 0); __builtin_amdgcn_s_setprio(0);
    if (!lastit) asm volatile("s_waitcnt vmcnt(6)" ::: "memory");
    __builtin_amdgcn_s_barrier();
  }

  // epilogue
  #pragma unroll
  for (int mt = 0; mt < 8; ++mt)
    #pragma unroll
    for (int nt = 0; nt < 4; ++nt) {
      const int ng = n0 + wn * 64 + nt * 16 + lr;
      const float sc = (DO_QSCALE && ng < 1024) ? 0.18033688f : 1.0f;
      #pragma unroll
      for (int r = 0; r < 4; ++r) {
        const int mg = m0 + wm * 128 + mt * 16 + 4 * lg + r;
        C[(size_t)mg * N + ng] = (__bf16)(acc[mt][nt][r] * sc);
      }
    }
  #undef WAIT_LGKM
}

// ---------------- V -> VT transpose with sigma key-permutation ------------
// grid: (T/64, B*H).  Reads V rows (QKV cols 2048..3071), writes VT[d][key'].
// Load: 4 threads/row x 2 bf16x8 = full 64 d per key row (R16 bug fixed).
// Write: destination slot s gathers source key ks = s0+2s1+16s2+4s3+8s4
// (inverse of the proven MODE-2 epilogue permutation).
__global__ __launch_bounds__(256) void vtrans_sigma(const __bf16* __restrict__ QKV,
                                                    __bf16* __restrict__ VT) {
  __shared__ alignas(16) __bf16 T[64][80];  // padded: 160B row stride
  const int t = threadIdx.x;
  const int kt = (int)blockIdx.x;   // key tile 0..31
  const int bh = (int)blockIdx.y;   // 0..63
  const int b = bh >> 4, h = bh & 15;
  const size_t bT = (size_t)b * T_SEQ;
  const int M = NB * T_SEQ;
  {
    const int r = t >> 2, cch = t & 3;  // key row r, 16-wide d-chunk cch
    const __bf16* src = QKV + (bT + kt * 64 + r) * QKS + 2048 + h * DK + cch * 16;
    const bf16x8 v0 = *reinterpret_cast<const bf16x8*>(src);
    const bf16x8 v1 = *reinterpret_cast<const bf16x8*>(src + 8);
    *reinterpret_cast<bf16x8*>(&T[r][cch * 16]) = v0;
    *reinterpret_cast<bf16x8*>(&T[r][cch * 16 + 8]) = v1;
  }
  __syncthreads();
  const int d = t >> 2, kc = t & 3;  // d row, 16-key output chunk
  __bf16* dst = VT + (size_t)(h * DK + d) * M + bT + kt * 64 + kc * 16;
  #pragma unroll
  for (int g = 0; g < 2; ++g) {
    bf16x8 o;
    #pragma unroll
    for (int j = 0; j < 8; ++j) {
      const int s = kc * 16 + g * 8 + j;
      const int s5 = s & 31;
      const int ks = (s & 32) | (s5 & 3) | (((s5 >> 2) & 1) << 4) | (((s5 >> 3) & 3) << 2);
      o[j] = T[ks][d];
    }
    *reinterpret_cast<bf16x8*>(dst + g * 8) = o;
  }
}

// ---------------- NT GEMM (m97-style, 128^2): C[M,N] = A[M,K] * B[N,K]^T --
template<typename CT>
__global__ __launch_bounds__(256, 2) void gemm_nt(const __bf16* __restrict__ A,
                                                  const __bf16* __restrict__ B,
                                                  CT* __restrict__ C,
                                                  int M, int N, int K) {
  __shared__ alignas(16) __bf16 As[128][64];
  __shared__ alignas(16) __bf16 Bs[128][64];
  const int tid = threadIdx.x;
  const int m0 = blockIdx.y * 128, n0 = blockIdx.x * 128;
  const int w = tid >> 6, l = tid & 63, lg = l >> 4, lr = l & 15;
  const int wr = (w >> 1) * 64, wc = (w & 1) * 64;
  const int srow = l >> 3;              // 0..7 within 8-row segment
  const int schunk = (l & 7) ^ srow;    // inverse-swizzled source 16B chunk

  f32x4 acc[4][4] = {};
  const int rsw = lr & 7;

  for (int k0 = 0; k0 < K; k0 += 64) {
    __syncthreads();
    #pragma unroll
    for (int j = 0; j < 4; ++j) {
      const int rbase = (w * 4 + j) * 8;
      gl_lds16(A + (size_t)(m0 + rbase + srow) * K + k0 + schunk * 8, &As[rbase][0]);
      gl_lds16(B + (size_t)(n0 + rbase + srow) * K + k0 + schunk * 8, &Bs[rbase][0]);
    }
    asm volatile("s_waitcnt vmcnt(0)" ::: "memory");
    __syncthreads();
    #pragma unroll
    for (int kk = 0; kk < 2; ++kk) {
      bf16x8 af[4], bfr[4];
      #pragma unroll
      for (int mt = 0; mt < 4; ++mt) {
        const char* p = (const char*)&As[wr + mt * 16 + lr][0];
        af[mt] = *reinterpret_cast<const bf16x8*>(p + (((kk * 4 + lg) ^ rsw) << 4));
      }
      #pragma unroll
      for (int nt = 0; nt < 4; ++nt) {
        const char* p = (const char*)&Bs[wc + nt * 16 + lr][0];
        bfr[nt] = *reinterpret_cast<const bf16x8*>(p + (((kk * 4 + lg) ^ rsw) << 4));
      }
      __builtin_amdgcn_s_setprio(1);
      #pragma unroll
      for (int mt = 0; mt < 4; ++mt)
        #pragma unroll
        for (int nt = 0; nt < 4; ++nt)
          acc[mt][nt] = __builtin_amdgcn_mfma_f32_16x16x32_bf16(af[mt], bfr[nt], acc[mt][nt], 0, 0, 0);
      __builtin_amdgcn_s_setprio(0);
    }
  }
  #pragma unroll
  for (int mt = 0; mt < 4; ++mt)
    #pragma unroll
    for (int nt = 0; nt < 4; ++nt)
      #pragma unroll
      for (int r = 0; r < 4; ++r) {
        const int mg = m0 + wr + mt * 16 + 4 * lg + r;
        const int ng = n0 + wc + nt * 16 + lr;
        C[(size_t)mg * N + ng] = (CT)acc[mt][nt][r];
      }
}

// ---------------- causal flash attention ----------------------------------
// grid: 512 blocks (8 per bh); XCD remap: bh = (f&7)*8|(f>>3)&7, c = f>>6.
// QUAD-chunk merge; no-max softmax with RAW v_exp_f32; swapped QK^T;
// sigma-permuted VT; l-sum via ones-column MFMA; 128-key staging.
__global__ __launch_bounds__(256, 2) void attn_fwd(const __bf16* __restrict__ QK,
                                                   const __bf16* __restrict__ VT,
                                                   __bf16* __restrict__ AO) {
  __shared__ alignas(16) __bf16 Ks[2][2][64][64];
  __shared__ alignas(16) __bf16 Vs[2][2][64][64];  // sigma-permuted V^T tiles
  const int tid = threadIdx.x;
  const int w = tid >> 6, l = tid & 63, lg = l >> 4, lr = l & 15;

  const int fl = (int)blockIdx.x + 8 * (int)blockIdx.y;  // dispatch order
  const int bh = ((fl & 7) << 3) | ((fl >> 3) & 7);
  const int c = fl >> 6;  // 0..7
  const int b = bh >> 4, h = bh & 15;
  const size_t bT = (size_t)b * T_SEQ;
  const int M = NB * T_SEQ;

  const int srow = l >> 3;
  const int schunk = (l & 7) ^ srow;  // inverse-swizzled source chunk
  const __bf16* Kg = QK + bT * QKS + 1024 + h * DK;   // K region of fused buffer
  const __bf16* Vg = VT + (size_t)(h * DK) * M + bT;
  const int rsw = lr & 7;

  // ones B-fragment for the l-sum MFMA (sum_k P[q][k] * 1)
  bf16x8 vone;
  #pragma unroll
  for (int j = 0; j < 8; ++j) vone[j] = (__bf16)1.0f;

  // chunk q-block indices (64-row chunks), nested activity A<=B<=C<=D
  const int qbA = c, qbB = 15 - c, qbC = 16 + c, qbD = 31 - c;
  const int qrwA = qbA * 64 + w * 16, qrwB = qbB * 64 + w * 16;
  const int qrwC = qbC * 64 + w * 16, qrwD = qbD * 64 + w * 16;
  const int klA = qbA * 64, klB = qbB * 64, klC = qbC * 64, klD = qbD * 64;

  const __bf16* QpA = QK + (bT + qrwA + lr) * QKS + h * DK;
  const __bf16* QpB = QK + (bT + qrwB + lr) * QKS + h * DK;
  const __bf16* QpC = QK + (bT + qrwC + lr) * QKS + h * DK;
  const __bf16* QpD = QK + (bT + qrwD + lr) * QKS + h * DK;
  const bf16x8 qfA0 = *reinterpret_cast<const bf16x8*>(QpA + 8 * lg);
  const bf16x8 qfA1 = *reinterpret_cast<const bf16x8*>(QpA + 32 + 8 * lg);
  const bf16x8 qfB0 = *reinterpret_cast<const bf16x8*>(QpB + 8 * lg);
  const bf16x8 qfB1 = *reinterpret_cast<const bf16x8*>(QpB + 32 + 8 * lg);
  const bf16x8 qfC0 = *reinterpret_cast<const bf16x8*>(QpC + 8 * lg);
  const bf16x8 qfC1 = *reinterpret_cast<const bf16x8*>(QpC + 32 + 8 * lg);
  const bf16x8 qfD0 = *reinterpret_cast<const bf16x8*>(QpD + 8 * lg);
  const bf16x8 qfD1 = *reinterpret_cast<const bf16x8*>(QpD + 32 + 8 * lg);

  f32x4 o_accA[4] = {}, o_accB[4] = {}, o_accC[4] = {}, o_accD[4] = {};
  f32x4 lA = {}, lB = {}, lC = {}, lD = {};

  // stage one 64x64 K + V sub-tile
  auto STAGE = [&](int buf, int st, int kbase) {
    #pragma unroll
    for (int i = 0; i < 2; ++i) {
      const int seg = w * 2 + i;
      gl_lds16(Kg + (size_t)(kbase + seg * 8 + srow) * QKS + schunk * 8,
               &Ks[buf][st][seg * 8][0]);
      gl_lds16(Vg + (size_t)(seg * 8 + srow) * M + kbase + schunk * 8,
               &Vs[buf][st][seg * 8][0]);
    }
  };

  // one chunk's tile: swapped QK^T -> P in-register -> PV + l via ones-MFMA
  auto CHUNK = [&](const bf16x8& qf0, const bf16x8& qf1, f32x4* o_acc,
                   f32x4& l_acc, int qrw, bool masked, int k0,
                   const bf16x8* kf, const bf16x8* vf) {
    f32x4 s[4] = {};
    __builtin_amdgcn_s_setprio(1);
    #pragma unroll
    for (int ct = 0; ct < 4; ++ct) {
      s[ct] = __builtin_amdgcn_mfma_f32_16x16x32_bf16(kf[2 * ct], qf0, s[ct], 0, 0, 0);
      s[ct] = __builtin_amdgcn_mfma_f32_16x16x32_bf16(kf[2 * ct + 1], qf1, s[ct], 0, 0, 0);
    }
    __builtin_amdgcn_s_setprio(0);
    if (masked) {  // causal: lane holds q=lr, key=k0+16ct+4lg+r
      #pragma unroll
      for (int ct = 0; ct < 4; ++ct)
        #pragma unroll
        for (int r = 0; r < 4; ++r)
          if (k0 + 16 * ct + 4 * lg + r > qrw + lr) s[ct][r] = -1e30f;
    }
    // P = 2^S (raw v_exp_f32: bounded S; -1e30 -> 0); pack to A-fragments
    unsigned pk[4][2];
    #pragma unroll
    for (int ct = 0; ct < 4; ++ct) {
      const float p0 = __builtin_amdgcn_exp2f(s[ct][0]);
      const float p1 = __builtin_amdgcn_exp2f(s[ct][1]);
      const float p2 = __builtin_amdgcn_exp2f(s[ct][2]);
      const float p3 = __builtin_amdgcn_exp2f(s[ct][3]);
      pk[ct][0] = cvt_pk_bf16(p0, p1);
      pk[ct][1] = cvt_pk_bf16(p2, p3);
    }
    const bf16x8 pf0 = __builtin_bit_cast(bf16x8, i32x4{(int)pk[0][0], (int)pk[0][1],
                                                        (int)pk[1][0], (int)pk[1][1]});
    const bf16x8 pf1 = __builtin_bit_cast(bf16x8, i32x4{(int)pk[2][0], (int)pk[2][1],
                                                        (int)pk[3][0], (int)pk[3][1]});
    __builtin_amdgcn_s_setprio(1);
    l_acc = __builtin_amdgcn_mfma_f32_16x16x32_bf16(pf0, vone, l_acc, 0, 0, 0);
    l_acc = __builtin_amdgcn_mfma_f32_16x16x32_bf16(pf1, vone, l_acc, 0, 0, 0);
    #pragma unroll
    for (int dt = 0; dt < 4; ++dt) {
      o_acc[dt] = __builtin_amdgcn_mfma_f32_16x16x32_bf16(pf0, vf[2 * dt],     o_acc[dt], 0, 0, 0);
      o_acc[dt] = __builtin_amdgcn_mfma_f32_16x16x32_bf16(pf1, vf[2 * dt + 1], o_acc[dt], 0, 0, 0);
    }
    __builtin_amdgcn_s_setprio(0);
  };

  // prologue: keys 0..127 (always valid: klD >= 1536)
  STAGE(0, 0, 0);
  STAGE(0, 1, 64);
  asm volatile("s_waitcnt vmcnt(0)" ::: "memory");
  __syncthreads();
  int buf = 0;

  for (int k0 = 0; k0 <= klD; k0 += 128) {
    if (k0 + 128 <= klD) STAGE(buf ^ 1, 0, k0 + 128);
    if (k0 + 192 <= klD) STAGE(buf ^ 1, 1, k0 + 192);

    #pragma unroll
    for (int st = 0; st < 2; ++st) {
      const int kk = k0 + st * 64;
      if (kk > klD) break;
      bf16x8 kf[8], vf[8];
      #pragma unroll
      for (int ct = 0; ct < 4; ++ct) {
        const char* kb = (const char*)&Ks[buf][st][ct * 16 + lr][0];
        kf[2 * ct]     = *reinterpret_cast<const bf16x8*>(kb + ((lg ^ rsw) << 4));
        kf[2 * ct + 1] = *reinterpret_cast<const bf16x8*>(kb + (((lg + 4) ^ rsw) << 4));
        const char* vb = (const char*)&Vs[buf][st][ct * 16 + lr][0];
        vf[2 * ct]     = *reinterpret_cast<const bf16x8*>(vb + ((lg ^ rsw) << 4));
        vf[2 * ct + 1] = *reinterpret_cast<const bf16x8*>(vb + (((lg + 4) ^ rsw) << 4));
      }
      CHUNK(qfD0, qfD1, o_accD, lD, qrwD, kk == klD, kk, kf, vf);
      if (kk <= klC) CHUNK(qfC0, qfC1, o_accC, lC, qrwC, kk == klC, kk, kf, vf);
      if (kk <= klB) CHUNK(qfB0, qfB1, o_accB, lB, qrwB, kk == klB, kk, kf, vf);
      if (kk <= klA) CHUNK(qfA0, qfA1, o_accA, lA, qrwA, kk == klA, kk, kf, vf);
    }

    asm volatile("s_waitcnt vmcnt(0)" ::: "memory");
    __syncthreads();
    buf ^= 1;
  }

  // --- output: l_acc rows align with o_acc rows (q = 4lg+r); no shuffles ---
  #pragma unroll
  for (int cc = 0; cc < 4; ++cc) {
    const f32x4& la = (cc == 0) ? lA : (cc == 1) ? lB : (cc == 2) ? lC : lD;
    f32x4* oa = (cc == 0) ? o_accA : (cc == 1) ? o_accB : (cc == 2) ? o_accC : o_accD;
    const int qrw = (cc == 0) ? qrwA : (cc == 1) ? qrwB : (cc == 2) ? qrwC : qrwD;
    #pragma unroll
    for (int r = 0; r < 4; ++r) {
      const float inv = 1.0f / la[r];
      #pragma unroll
      for (int dt = 0; dt < 4; ++dt) {
        const int rg = qrw + 4 * lg + r;
        const int cg = h * DK + dt * 16 + lr;
        AO[(bT + rg) * DM + cg] = (__bf16)(oa[dt][r] * inv);
      }
    }
  }
}

extern "C" void kernel_launch(void* const* d_in, const int* in_sizes, int n_in,
                              void* d_out, int out_size, void* d_ws, size_t ws_size,
                              hipStream_t stream) {
  (void)in_sizes; (void)n_in; (void)out_size; (void)ws_size;
  const float* X  = (const float*)d_in[0];
  const float* Wq = (const float*)d_in[1];
  const float* Wk = (const float*)d_in[2];
  const float* Wv = (const float*)d_in[3];
  const float* Wo = (const float*)d_in[4];
  float* OUT = (float*)d_out;

  char* ws = (char*)d_ws;
  const size_t SZ_X   = (size_t)NB * T_SEQ * DM * 2;   // 16.78 MB
  const size_t SZ_W   = (size_t)DM * DM * 2;           // 2.10 MB
  const size_t SZ_QKV = (size_t)NB * T_SEQ * QKS * 2;  // 50.33 MB
  __bf16* Xb   = (__bf16*)ws; ws += SZ_X;
  __bf16* Wqb  = (__bf16*)ws; ws += SZ_W;   // Wqb,Wkb,Wvb contiguous ->
  __bf16* Wkb  = (__bf16*)ws; ws += SZ_W;   // fused [Wq;Wk;Wv] of 3072x1024
  __bf16* Wvb  = (__bf16*)ws; ws += SZ_W;
  __bf16* Wob  = (__bf16*)ws; ws += SZ_W;
  __bf16* QKVb = (__bf16*)ws; ws += SZ_QKV;
  __bf16* VTb  = (__bf16*)ws; ws += SZ_X;
  __bf16* AOb  = Xb;  // X dead after QKV GEMM; attn output reuses its space

  const int M = NB * T_SEQ;  // 8192

  // fused cast: X (8192 blocks) + 4 weights (4096 blocks)
  cast_all<<<(M * DM / 4 + 4 * DM * DM / 4) / 256, 256, 0, stream>>>(
      X, Wq, Wk, Wv, Wo, Xb, Wqb, Wkb, Wvb, Wob);

  // [Q|K|V] = X @ [Wq;Wk;Wv]^T via 256^2 8-phase; Q cols scaled 0.125*log2e
  gemm_nt_8p<1><<<(M / 256) * (QKS / 256), 512, 0, stream>>>(Xb, Wqb, QKVb, M, QKS, DM);
  // VT[d][key'] = sigma-permuted V^T (transpose of QKV's V region)
  vtrans_sigma<<<dim3(T_SEQ / 64, NB * NH), 256, 0, stream>>>(QKVb, VTb);
  // attention (512 blocks, quad-chunk, 128-key staging)
  attn_fwd<<<dim3(8, NB * NH), 256, 0, stream>>>(QKVb, VTb, AOb);
  // OUT = AO @ Wo^T (fp32 out)
  gemm_nt<float><<<dim3(DM / 128, M / 128), 256, 0, stream>>>(AOb, Wob, OUT, M, DM, DM);
}

// Round 18
// 142.098 us; speedup vs baseline: 1.1382x; 1.1382x over previous
//
#include <hip/hip_runtime.h>
#include <hip/hip_bf16.h>

#define T_SEQ 2048
#define NB 4
#define NH 16
#define DK 64
#define DM 1024
#define QKS 2048  // row stride of fused [Q|K] buffer

typedef __attribute__((ext_vector_type(8))) __bf16 bf16x8;
typedef __attribute__((ext_vector_type(4))) __bf16 bf16x4;
typedef __attribute__((ext_vector_type(4))) float f32x4;
typedef __attribute__((ext_vector_type(2))) int i32x2;
typedef __attribute__((ext_vector_type(4))) int i32x4;

// async global->LDS, 16B per lane, wave-uniform LDS base + lane*16
__device__ __forceinline__ void gl_lds16(const __bf16* g, __bf16* l) {
  __builtin_amdgcn_global_load_lds(
      (const __attribute__((address_space(1))) void*)g,
      (__attribute__((address_space(3))) void*)l,
      16, 0, 0);
}

__device__ __forceinline__ unsigned cvt_pk_bf16(float lo, float hi) {
  unsigned r;
  asm("v_cvt_pk_bf16_f32 %0, %1, %2" : "=v"(r) : "v"(lo), "v"(hi));
  return r;
}

// ---------------- fused cast: X + 4 weights, 32B per lane ----------------
__global__ __launch_bounds__(256) void cast_all(const float* __restrict__ X,
                                                const float* __restrict__ Wq,
                                                const float* __restrict__ Wk,
                                                const float* __restrict__ Wv,
                                                const float* __restrict__ Wo,
                                                __bf16* __restrict__ Xb,
                                                __bf16* __restrict__ Wqb,
                                                __bf16* __restrict__ Wkb,
                                                __bf16* __restrict__ Wvb,
                                                __bf16* __restrict__ Wob) {
  const int NX4 = NB * T_SEQ * DM / 4;  // 2,097,152 (even)
  const int NW4 = DM * DM / 4;          // 262,144 = 1<<18 (even)
  const int p = blockIdx.x * 256 + threadIdx.x;  // float4-PAIR index
  const int i = p * 2;
  const float* in;
  __bf16* out;
  int idx;
  if (i < NX4) {
    in = X; out = Xb; idx = i;
  } else {
    const int j = i - NX4;
    const int w = j >> 18;
    idx = j & (NW4 - 1);
    in = (w == 0) ? Wq : (w == 1) ? Wk : (w == 2) ? Wv : Wo;
    out = (w == 0) ? Wqb : (w == 1) ? Wkb : (w == 2) ? Wvb : Wob;
  }
  #pragma unroll
  for (int u = 0; u < 2; ++u) {
    float4 v = reinterpret_cast<const float4*>(in)[idx + u];
    bf16x4 o;
    o[0] = (__bf16)v.x; o[1] = (__bf16)v.y; o[2] = (__bf16)v.z; o[3] = (__bf16)v.w;
    reinterpret_cast<bf16x4*>(out)[idx + u] = o;
  }
}

// ---------------- 256x256 8-phase GEMM (T3+T4+T5): C = A * B^T ------------
template<int DO_QSCALE>
__global__ __launch_bounds__(512, 2) void gemm_nt_8p(const __bf16* __restrict__ A,
                                                     const __bf16* __restrict__ Bm,
                                                     __bf16* __restrict__ C,
                                                     int M, int N, int K) {
  __shared__ alignas(16) __bf16 As[2][256][64];
  __shared__ alignas(16) __bf16 Bs[2][256][64];
  const int tid = threadIdx.x;
  const int wid = tid >> 6, l = tid & 63, lg = l >> 4, lr = l & 15;
  const int wm = wid >> 2, wn = wid & 3;
  // bijective XCD swizzle (gridDim.x % 8 == 0)
  const int f = (int)blockIdx.x;
  const int cpx = (int)gridDim.x >> 3;
  const int swz = (f & 7) * cpx + (f >> 3);
  const int nbn = N >> 8;
  const int m0 = (swz / nbn) << 8, n0 = (swz % nbn) << 8;

  const int srow = l >> 3;
  const int schunk = (l & 7) ^ srow;  // inverse-swizzled source chunk
  const int rsw = lr & 7;
  const int strow = wid * 8 + srow;   // staging row within a 64-row group

  f32x4 acc[8][4] = {};
  bf16x8 aA[8], bB[8];

  auto SA = [&](int buf, int half, int t) {
    #pragma unroll
    for (int j = 0; j < 2; ++j)
      gl_lds16(A + (size_t)(m0 + half * 128 + j * 64 + strow) * K + t * 64 + schunk * 8,
               &As[buf][half * 128 + j * 64 + wid * 8][0]);
  };
  auto SB = [&](int buf, int half, int t) {
    #pragma unroll
    for (int j = 0; j < 2; ++j)
      gl_lds16(Bm + (size_t)(n0 + half * 128 + j * 64 + strow) * K + t * 64 + schunk * 8,
               &Bs[buf][half * 128 + j * 64 + wid * 8][0]);
  };
  auto LA = [&](int buf, int mh) {
    #pragma unroll
    for (int mt = 0; mt < 4; ++mt) {
      const char* p = (const char*)&As[buf][wm * 128 + mh * 64 + mt * 16 + lr][0];
      aA[mt * 2 + 0] = *reinterpret_cast<const bf16x8*>(p + ((lg ^ rsw) << 4));
      aA[mt * 2 + 1] = *reinterpret_cast<const bf16x8*>(p + (((4 + lg) ^ rsw) << 4));
    }
  };
  auto LBh = [&](int buf, int nh) {
    #pragma unroll
    for (int ntl = 0; ntl < 2; ++ntl) {
      const int nt = nh * 2 + ntl;
      const char* p = (const char*)&Bs[buf][wn * 64 + nt * 16 + lr][0];
      bB[nt * 2 + 0] = *reinterpret_cast<const bf16x8*>(p + ((lg ^ rsw) << 4));
      bB[nt * 2 + 1] = *reinterpret_cast<const bf16x8*>(p + (((4 + lg) ^ rsw) << 4));
    }
  };
  auto MQ = [&](int mh, int nh) {
    #pragma unroll
    for (int mt = 0; mt < 4; ++mt)
      #pragma unroll
      for (int ntl = 0; ntl < 2; ++ntl) {
        const int nt = nh * 2 + ntl;
        acc[mh * 4 + mt][nt] = __builtin_amdgcn_mfma_f32_16x16x32_bf16(
            aA[mt * 2 + 0], bB[nt * 2 + 0], acc[mh * 4 + mt][nt], 0, 0, 0);
        acc[mh * 4 + mt][nt] = __builtin_amdgcn_mfma_f32_16x16x32_bf16(
            aA[mt * 2 + 1], bB[nt * 2 + 1], acc[mh * 4 + mt][nt], 0, 0, 0);
      }
  };
  #define WAIT_LGKM() do { asm volatile("s_waitcnt lgkmcnt(0)" ::: "memory"); \
                           __builtin_amdgcn_sched_barrier(0); } while (0)

  // prologue: tile0 full (8) + tile1 {B0,B1,A0} (6) = 14 outstanding
  SB(0, 0, 0); SB(0, 1, 0); SA(0, 0, 0); SA(0, 1, 0);
  SB(1, 0, 1); SB(1, 1, 1); SA(1, 0, 1);
  asm volatile("s_waitcnt vmcnt(6)" ::: "memory");  // tile0 landed
  __builtin_amdgcn_s_barrier();

  const int NIT = K >> 7;
  for (int i = 0; i < NIT; ++i) {
    const bool lastit = (i == NIT - 1);
    const int t2 = 2 * i + 2, t3 = 2 * i + 3;
    // P1: reads A0h0+B-nh0 (12); stage tile(2i+1).Ah1
    LA(0, 0); LBh(0, 0);
    SA(1, 1, 2 * i + 1);
    __builtin_amdgcn_s_barrier();
    WAIT_LGKM();
    __builtin_amdgcn_s_setprio(1); MQ(0, 0); __builtin_amdgcn_s_setprio(0);
    __builtin_amdgcn_s_barrier();
    // P2: reads B-nh1 (4); no staging
    LBh(0, 1);
    WAIT_LGKM();
    __builtin_amdgcn_s_setprio(1); MQ(0, 1); __builtin_amdgcn_s_setprio(0);
    __builtin_amdgcn_s_barrier();
    // P3: reads A0h1 (8); stage t+2.B both halves
    LA(0, 1);
    if (!lastit) { SB(0, 0, t2); SB(0, 1, t2); }
    __builtin_amdgcn_s_barrier();
    WAIT_LGKM();
    __builtin_amdgcn_s_setprio(1); MQ(1, 1); __builtin_amdgcn_s_setprio(0);
    __builtin_amdgcn_s_barrier();
    // P4: stage t+2.Ah0; wait tile 2i+1 landed
    if (!lastit) SA(0, 0, t2);
    __builtin_amdgcn_s_setprio(1); MQ(1, 0); __builtin_amdgcn_s_setprio(0);
    if (lastit) asm volatile("s_waitcnt vmcnt(0)" ::: "memory");
    else        asm volatile("s_waitcnt vmcnt(6)" ::: "memory");
    __builtin_amdgcn_s_barrier();
    // P5: reads buf1 A0h0+B-nh0 (12); stage t+2.Ah1
    LA(1, 0); LBh(1, 0);
    if (!lastit) SA(0, 1, t2);
    __builtin_amdgcn_s_barrier();
    WAIT_LGKM();
    __builtin_amdgcn_s_setprio(1); MQ(0, 0); __builtin_amdgcn_s_setprio(0);
    __builtin_amdgcn_s_barrier();
    // P6: reads B-nh1 (4); no staging
    LBh(1, 1);
    WAIT_LGKM();
    __builtin_amdgcn_s_setprio(1); MQ(0, 1); __builtin_amdgcn_s_setprio(0);
    __builtin_amdgcn_s_barrier();
    // P7: reads A1h1 (8); stage t+3.B both halves
    LA(1, 1);
    if (!lastit) { SB(1, 0, t3); SB(1, 1, t3); }
    __builtin_amdgcn_s_barrier();
    WAIT_LGKM();
    __builtin_amdgcn_s_setprio(1); MQ(1, 1); __builtin_amdgcn_s_setprio(0);
    __builtin_amdgcn_s_barrier();
    // P8: stage t+3.Ah0; wait tile 2i+2 landed
    if (!lastit) SA(1, 0, t3);
    __builtin_amdgcn_s_setprio(1); MQ(1, 0); __builtin_amdgcn_s_setprio(0);
    if (!lastit) asm volatile("s_waitcnt vmcnt(6)" ::: "memory");
    __builtin_amdgcn_s_barrier();
  }

  // epilogue
  #pragma unroll
  for (int mt = 0; mt < 8; ++mt)
    #pragma unroll
    for (int nt = 0; nt < 4; ++nt) {
      const int ng = n0 + wn * 64 + nt * 16 + lr;
      const float sc = (DO_QSCALE && ng < 1024) ? 0.18033688f : 1.0f;
      #pragma unroll
      for (int r = 0; r < 4; ++r) {
        const int mg = m0 + wm * 128 + mt * 16 + 4 * lg + r;
        C[(size_t)mg * N + ng] = (__bf16)(acc[mt][nt][r] * sc);
      }
    }
  #undef WAIT_LGKM
}

// ---------------- NT GEMM (m97-style, 128^2): C[M,N] = A[M,K] * B[N,K]^T --
// MODE 0: plain.  MODE 2: sigma-permute N within 32-groups (VT).
template<typename CT, int MODE>
__global__ __launch_bounds__(256, 2) void gemm_nt(const __bf16* __restrict__ A,
                                                  const __bf16* __restrict__ B,
                                                  CT* __restrict__ C,
                                                  int M, int N, int K) {
  __shared__ alignas(16) __bf16 As[128][64];
  __shared__ alignas(16) __bf16 Bs[128][64];
  const int tid = threadIdx.x;
  const int m0 = blockIdx.y * 128, n0 = blockIdx.x * 128;
  const int w = tid >> 6, l = tid & 63, lg = l >> 4, lr = l & 15;
  const int wr = (w >> 1) * 64, wc = (w & 1) * 64;
  const int srow = l >> 3;              // 0..7 within 8-row segment
  const int schunk = (l & 7) ^ srow;    // inverse-swizzled source 16B chunk

  f32x4 acc[4][4] = {};
  const int rsw = lr & 7;

  for (int k0 = 0; k0 < K; k0 += 64) {
    __syncthreads();
    #pragma unroll
    for (int j = 0; j < 4; ++j) {
      const int rbase = (w * 4 + j) * 8;
      gl_lds16(A + (size_t)(m0 + rbase + srow) * K + k0 + schunk * 8, &As[rbase][0]);
      gl_lds16(B + (size_t)(n0 + rbase + srow) * K + k0 + schunk * 8, &Bs[rbase][0]);
    }
    asm volatile("s_waitcnt vmcnt(0)" ::: "memory");
    __syncthreads();
    #pragma unroll
    for (int kk = 0; kk < 2; ++kk) {
      bf16x8 af[4], bfr[4];
      #pragma unroll
      for (int mt = 0; mt < 4; ++mt) {
        const char* p = (const char*)&As[wr + mt * 16 + lr][0];
        af[mt] = *reinterpret_cast<const bf16x8*>(p + (((kk * 4 + lg) ^ rsw) << 4));
      }
      #pragma unroll
      for (int nt = 0; nt < 4; ++nt) {
        const char* p = (const char*)&Bs[wc + nt * 16 + lr][0];
        bfr[nt] = *reinterpret_cast<const bf16x8*>(p + (((kk * 4 + lg) ^ rsw) << 4));
      }
      __builtin_amdgcn_s_setprio(1);
      #pragma unroll
      for (int mt = 0; mt < 4; ++mt)
        #pragma unroll
        for (int nt = 0; nt < 4; ++nt)
          acc[mt][nt] = __builtin_amdgcn_mfma_f32_16x16x32_bf16(af[mt], bfr[nt], acc[mt][nt], 0, 0, 0);
      __builtin_amdgcn_s_setprio(0);
    }
  }
  #pragma unroll
  for (int mt = 0; mt < 4; ++mt)
    #pragma unroll
    for (int nt = 0; nt < 4; ++nt)
      #pragma unroll
      for (int r = 0; r < 4; ++r) {
        const int mg = m0 + wr + mt * 16 + 4 * lg + r;
        int ng = n0 + wc + nt * 16 + lr;
        if (MODE == 2)  // sigma^-1 within 32-key group: key kappa -> slot
          ng = (ng & ~31) | (8 * (lr >> 2) + (lr & 3) + ((nt & 1) << 2));
        C[(size_t)mg * N + ng] = (CT)acc[mt][nt][r];
      }
}

// ---------------- causal flash attention ----------------------------------
// grid: 512 blocks (8 per bh); XCD remap: bh = (f&7)*8|(f>>3)&7, c = f>>6.
// QUAD-chunk merge; no-max softmax with RAW v_exp_f32; swapped QK^T;
// sigma-permuted VT; l-sum via ones-column MFMA; 128-key staging.
__global__ __launch_bounds__(256, 2) void attn_fwd(const __bf16* __restrict__ QK,
                                                   const __bf16* __restrict__ VT,
                                                   __bf16* __restrict__ AO) {
  __shared__ alignas(16) __bf16 Ks[2][2][64][64];
  __shared__ alignas(16) __bf16 Vs[2][2][64][64];  // sigma-permuted V^T tiles
  const int tid = threadIdx.x;
  const int w = tid >> 6, l = tid & 63, lg = l >> 4, lr = l & 15;

  const int fl = (int)blockIdx.x + 8 * (int)blockIdx.y;  // dispatch order
  const int bh = ((fl & 7) << 3) | ((fl >> 3) & 7);
  const int c = fl >> 6;  // 0..7
  const int b = bh >> 4, h = bh & 15;
  const size_t bT = (size_t)b * T_SEQ;
  const int M = NB * T_SEQ;

  const int srow = l >> 3;
  const int schunk = (l & 7) ^ srow;  // inverse-swizzled source chunk
  const __bf16* Kg = QK + bT * QKS + 1024 + h * DK;   // K half of fused buffer
  const __bf16* Vg = VT + (size_t)(h * DK) * M + bT;
  const int rsw = lr & 7;

  // ones B-fragment for the l-sum MFMA (sum_k P[q][k] * 1)
  bf16x8 vone;
  #pragma unroll
  for (int j = 0; j < 8; ++j) vone[j] = (__bf16)1.0f;

  // chunk q-block indices (64-row chunks), nested activity A<=B<=C<=D
  const int qbA = c, qbB = 15 - c, qbC = 16 + c, qbD = 31 - c;
  const int qrwA = qbA * 64 + w * 16, qrwB = qbB * 64 + w * 16;
  const int qrwC = qbC * 64 + w * 16, qrwD = qbD * 64 + w * 16;
  const int klA = qbA * 64, klB = qbB * 64, klC = qbC * 64, klD = qbD * 64;

  const __bf16* QpA = QK + (bT + qrwA + lr) * QKS + h * DK;
  const __bf16* QpB = QK + (bT + qrwB + lr) * QKS + h * DK;
  const __bf16* QpC = QK + (bT + qrwC + lr) * QKS + h * DK;
  const __bf16* QpD = QK + (bT + qrwD + lr) * QKS + h * DK;
  const bf16x8 qfA0 = *reinterpret_cast<const bf16x8*>(QpA + 8 * lg);
  const bf16x8 qfA1 = *reinterpret_cast<const bf16x8*>(QpA + 32 + 8 * lg);
  const bf16x8 qfB0 = *reinterpret_cast<const bf16x8*>(QpB + 8 * lg);
  const bf16x8 qfB1 = *reinterpret_cast<const bf16x8*>(QpB + 32 + 8 * lg);
  const bf16x8 qfC0 = *reinterpret_cast<const bf16x8*>(QpC + 8 * lg);
  const bf16x8 qfC1 = *reinterpret_cast<const bf16x8*>(QpC + 32 + 8 * lg);
  const bf16x8 qfD0 = *reinterpret_cast<const bf16x8*>(QpD + 8 * lg);
  const bf16x8 qfD1 = *reinterpret_cast<const bf16x8*>(QpD + 32 + 8 * lg);

  f32x4 o_accA[4] = {}, o_accB[4] = {}, o_accC[4] = {}, o_accD[4] = {};
  f32x4 lA = {}, lB = {}, lC = {}, lD = {};

  // stage one 64x64 K + V sub-tile
  auto STAGE = [&](int buf, int st, int kbase) {
    #pragma unroll
    for (int i = 0; i < 2; ++i) {
      const int seg = w * 2 + i;
      gl_lds16(Kg + (size_t)(kbase + seg * 8 + srow) * QKS + schunk * 8,
               &Ks[buf][st][seg * 8][0]);
      gl_lds16(Vg + (size_t)(seg * 8 + srow) * M + kbase + schunk * 8,
               &Vs[buf][st][seg * 8][0]);
    }
  };

  // one chunk's tile: swapped QK^T -> P in-register -> PV + l via ones-MFMA
  auto CHUNK = [&](const bf16x8& qf0, const bf16x8& qf1, f32x4* o_acc,
                   f32x4& l_acc, int qrw, bool masked, int k0,
                   const bf16x8* kf, const bf16x8* vf) {
    f32x4 s[4] = {};
    __builtin_amdgcn_s_setprio(1);
    #pragma unroll
    for (int ct = 0; ct < 4; ++ct) {
      s[ct] = __builtin_amdgcn_mfma_f32_16x16x32_bf16(kf[2 * ct], qf0, s[ct], 0, 0, 0);
      s[ct] = __builtin_amdgcn_mfma_f32_16x16x32_bf16(kf[2 * ct + 1], qf1, s[ct], 0, 0, 0);
    }
    __builtin_amdgcn_s_setprio(0);
    if (masked) {  // causal: lane holds q=lr, key=k0+16ct+4lg+r
      #pragma unroll
      for (int ct = 0; ct < 4; ++ct)
        #pragma unroll
        for (int r = 0; r < 4; ++r)
          if (k0 + 16 * ct + 4 * lg + r > qrw + lr) s[ct][r] = -1e30f;
    }
    // P = 2^S (raw v_exp_f32: bounded S; -1e30 -> 0); pack to A-fragments
    unsigned pk[4][2];
    #pragma unroll
    for (int ct = 0; ct < 4; ++ct) {
      const float p0 = __builtin_amdgcn_exp2f(s[ct][0]);
      const float p1 = __builtin_amdgcn_exp2f(s[ct][1]);
      const float p2 = __builtin_amdgcn_exp2f(s[ct][2]);
      const float p3 = __builtin_amdgcn_exp2f(s[ct][3]);
      pk[ct][0] = cvt_pk_bf16(p0, p1);
      pk[ct][1] = cvt_pk_bf16(p2, p3);
    }
    const bf16x8 pf0 = __builtin_bit_cast(bf16x8, i32x4{(int)pk[0][0], (int)pk[0][1],
                                                        (int)pk[1][0], (int)pk[1][1]});
    const bf16x8 pf1 = __builtin_bit_cast(bf16x8, i32x4{(int)pk[2][0], (int)pk[2][1],
                                                        (int)pk[3][0], (int)pk[3][1]});
    __builtin_amdgcn_s_setprio(1);
    l_acc = __builtin_amdgcn_mfma_f32_16x16x32_bf16(pf0, vone, l_acc, 0, 0, 0);
    l_acc = __builtin_amdgcn_mfma_f32_16x16x32_bf16(pf1, vone, l_acc, 0, 0, 0);
    #pragma unroll
    for (int dt = 0; dt < 4; ++dt) {
      o_acc[dt] = __builtin_amdgcn_mfma_f32_16x16x32_bf16(pf0, vf[2 * dt],     o_acc[dt], 0, 0, 0);
      o_acc[dt] = __builtin_amdgcn_mfma_f32_16x16x32_bf16(pf1, vf[2 * dt + 1], o_acc[dt], 0, 0, 0);
    }
    __builtin_amdgcn_s_setprio(0);
  };

  // prologue: keys 0..127 (always valid: klD >= 1536)
  STAGE(0, 0, 0);
  STAGE(0, 1, 64);
  asm volatile("s_waitcnt vmcnt(0)" ::: "memory");
  __syncthreads();
  int buf = 0;

  for (int k0 = 0; k0 <= klD; k0 += 128) {
    if (k0 + 128 <= klD) STAGE(buf ^ 1, 0, k0 + 128);
    if (k0 + 192 <= klD) STAGE(buf ^ 1, 1, k0 + 192);

    #pragma unroll
    for (int st = 0; st < 2; ++st) {
      const int kk = k0 + st * 64;
      if (kk > klD) break;
      bf16x8 kf[8], vf[8];
      #pragma unroll
      for (int ct = 0; ct < 4; ++ct) {
        const char* kb = (const char*)&Ks[buf][st][ct * 16 + lr][0];
        kf[2 * ct]     = *reinterpret_cast<const bf16x8*>(kb + ((lg ^ rsw) << 4));
        kf[2 * ct + 1] = *reinterpret_cast<const bf16x8*>(kb + (((lg + 4) ^ rsw) << 4));
        const char* vb = (const char*)&Vs[buf][st][ct * 16 + lr][0];
        vf[2 * ct]     = *reinterpret_cast<const bf16x8*>(vb + ((lg ^ rsw) << 4));
        vf[2 * ct + 1] = *reinterpret_cast<const bf16x8*>(vb + (((lg + 4) ^ rsw) << 4));
      }
      CHUNK(qfD0, qfD1, o_accD, lD, qrwD, kk == klD, kk, kf, vf);
      if (kk <= klC) CHUNK(qfC0, qfC1, o_accC, lC, qrwC, kk == klC, kk, kf, vf);
      if (kk <= klB) CHUNK(qfB0, qfB1, o_accB, lB, qrwB, kk == klB, kk, kf, vf);
      if (kk <= klA) CHUNK(qfA0, qfA1, o_accA, lA, qrwA, kk == klA, kk, kf, vf);
    }

    asm volatile("s_waitcnt vmcnt(0)" ::: "memory");
    __syncthreads();
    buf ^= 1;
  }

  // --- output: l_acc rows align with o_acc rows (q = 4lg+r); no shuffles ---
  #pragma unroll
  for (int cc = 0; cc < 4; ++cc) {
    const f32x4& la = (cc == 0) ? lA : (cc == 1) ? lB : (cc == 2) ? lC : lD;
    f32x4* oa = (cc == 0) ? o_accA : (cc == 1) ? o_accB : (cc == 2) ? o_accC : o_accD;
    const int qrw = (cc == 0) ? qrwA : (cc == 1) ? qrwB : (cc == 2) ? qrwC : qrwD;
    #pragma unroll
    for (int r = 0; r < 4; ++r) {
      const float inv = 1.0f / la[r];
      #pragma unroll
      for (int dt = 0; dt < 4; ++dt) {
        const int rg = qrw + 4 * lg + r;
        const int cg = h * DK + dt * 16 + lr;
        AO[(bT + rg) * DM + cg] = (__bf16)(oa[dt][r] * inv);
      }
    }
  }
}

extern "C" void kernel_launch(void* const* d_in, const int* in_sizes, int n_in,
                              void* d_out, int out_size, void* d_ws, size_t ws_size,
                              hipStream_t stream) {
  (void)in_sizes; (void)n_in; (void)out_size; (void)ws_size;
  const float* X  = (const float*)d_in[0];
  const float* Wq = (const float*)d_in[1];
  const float* Wk = (const float*)d_in[2];
  const float* Wv = (const float*)d_in[3];
  const float* Wo = (const float*)d_in[4];
  float* OUT = (float*)d_out;

  char* ws = (char*)d_ws;
  const size_t SZ_X  = (size_t)NB * T_SEQ * DM * 2;   // 16.78 MB
  const size_t SZ_W  = (size_t)DM * DM * 2;           // 2.10 MB
  const size_t SZ_QK = (size_t)NB * T_SEQ * QKS * 2;  // 33.55 MB
  __bf16* Xb  = (__bf16*)ws; ws += SZ_X;
  __bf16* Wqb = (__bf16*)ws; ws += SZ_W;   // Wqb and Wkb contiguous ->
  __bf16* Wkb = (__bf16*)ws; ws += SZ_W;   // fused [Wq;Wk] of 2048x1024
  __bf16* Wvb = (__bf16*)ws; ws += SZ_W;
  __bf16* Wob = (__bf16*)ws; ws += SZ_W;
  __bf16* QKb = (__bf16*)ws; ws += SZ_QK;
  __bf16* VTb = (__bf16*)ws; ws += SZ_X;
  __bf16* AOb = (__bf16*)ws; ws += SZ_X;

  const int M = NB * T_SEQ;  // 8192

  // fused cast, 32B/lane: (NX4 + 4*NW4)/2 pairs = 6144 blocks
  cast_all<<<(M * DM / 4 + 4 * DM * DM / 4) / 2 / 256, 256, 0, stream>>>(
      X, Wq, Wk, Wv, Wo, Xb, Wqb, Wkb, Wvb, Wob);

  // [Q|K] = X @ [Wq;Wk]^T via 256^2 8-phase; Q cols pre-scaled by 0.125*log2e
  gemm_nt_8p<1><<<(M / 256) * (QKS / 256), 512, 0, stream>>>(Xb, Wqb, QKb, M, QKS, DM);
  // VT[d][key'] = sigma-permuted V^T  (V = X @ Wv^T)
  gemm_nt<__bf16, 2><<<dim3(M / 128, DM / 128), 256, 0, stream>>>(Wvb, Xb, VTb, DM, M, DM);
  // attention (512 blocks, quad-chunk, 128-key staging)
  attn_fwd<<<dim3(8, NB * NH), 256, 0, stream>>>(QKb, VTb, AOb);
  // OUT = AO @ Wo^T (fp32 out)
  gemm_nt<float, 0><<<dim3(DM / 128, M / 128), 256, 0, stream>>>(AOb, Wob, OUT, M, DM, DM);
}